// Round 1
// baseline (2854.341 us; speedup 1.0000x reference)
//
#include <hip/hip_runtime.h>

#define N_ 32
#define C_ 64
#define T_ 64
#define V_ 204
#define H_ 3
#define TV_ (T_ * V_)          // 13056
#define CTV_ (C_ * TV_)        // 835584
#define VG_ (V_ / 4)           // 51
#define NH_ (N_ * H_)          // 96
#define EPS_ 1e-5f
#define ATT_SC_ (1.0f / 3264.0f)

// ---------------------------------------------------------------------------
// K1: g = relu(bn(einsum('uv,nctv->nctu', A, W@x + b)) + x)
// block = (t, n), 256 threads
// ---------------------------------------------------------------------------
__global__ __launch_bounds__(256) void k1_gcn(
    const float* __restrict__ x, const float* __restrict__ A,
    const float* __restrict__ W, const float* __restrict__ bias,
    const float* __restrict__ bng, const float* __restrict__ bnb,
    const float* __restrict__ bnm, const float* __restrict__ bnv,
    float* __restrict__ g_out)
{
    __shared__ float Hs[C_ * 208];
    const int t = blockIdx.x, n = blockIdx.y;
    const int tid = threadIdx.x;
    const float* xp = x + (size_t)n * CTV_ + (size_t)t * V_;

    // Phase B: Hs[c][v] = bias[c] + sum_a W[c,a]*x[n,a,t,v]; lane = v
    if (tid < V_) {
        float xc[C_];
#pragma unroll
        for (int a = 0; a < C_; ++a) xc[a] = xp[(size_t)a * TV_ + tid];
#pragma unroll 1
        for (int c = 0; c < C_; ++c) {
            float acc = bias[c];
#pragma unroll
            for (int a = 0; a < C_; ++a) acc = fmaf(W[c * C_ + a], xc[a], acc);
            Hs[c * 208 + tid] = acc;
        }
    }
    __syncthreads();

    // Phase C: out[c,u] = sum_v A[u,v]*Hs[c][v]; 8u x 8c register tile
    const int task = tid;
    if (task < 208) {
        const int ug = task % 26, cg = task / 26;
        const int u0 = ug * 8;
        const int nu = (u0 + 8 <= V_) ? 8 : (V_ - u0);   // last group has 4
        const int c0 = cg * 8;
        float acc[8][8];
#pragma unroll
        for (int i = 0; i < 8; ++i)
#pragma unroll
            for (int j = 0; j < 8; ++j) acc[i][j] = 0.f;

#pragma unroll 1
        for (int vg = 0; vg < VG_; ++vg) {
            float4 a4[8];
#pragma unroll
            for (int i = 0; i < 8; ++i) {
                if (i < nu) a4[i] = *(const float4*)(A + (u0 + i) * V_ + vg * 4);
                else        a4[i] = make_float4(0.f, 0.f, 0.f, 0.f);
            }
#pragma unroll
            for (int j = 0; j < 8; ++j) {
                float4 h4 = *(const float4*)(&Hs[(c0 + j) * 208 + vg * 4]);
#pragma unroll
                for (int i = 0; i < 8; ++i) {
                    acc[i][j] = fmaf(a4[i].x, h4.x, acc[i][j]);
                    acc[i][j] = fmaf(a4[i].y, h4.y, acc[i][j]);
                    acc[i][j] = fmaf(a4[i].z, h4.z, acc[i][j]);
                    acc[i][j] = fmaf(a4[i].w, h4.w, acc[i][j]);
                }
            }
        }

        float* gp = g_out + (size_t)n * CTV_ + (size_t)t * V_;
#pragma unroll 1
        for (int j = 0; j < 8; ++j) {
            const int c = c0 + j;
            const float s  = bng[c] * rsqrtf(bnv[c] + EPS_);
            const float sh = bnb[c] - bnm[c] * s;
            const float* xr = xp + (size_t)c * TV_;
            float* gr = gp + (size_t)c * TV_;
            float tmp[8];
#pragma unroll
            for (int i = 0; i < 8; ++i) {
                float xv  = (i < nu) ? xr[u0 + i] : 0.f;
                float val = acc[i][j] * s + sh + xv;
                tmp[i] = fmaxf(val, 0.f);
            }
            *(float4*)(gr + u0) = make_float4(tmp[0], tmp[1], tmp[2], tmp[3]);
            if (nu == 8)
                *(float4*)(gr + u0 + 4) = make_float4(tmp[4], tmp[5], tmp[6], tmp[7]);
        }
    }
}

// ---------------------------------------------------------------------------
// K2: qk[n, j, t, v] = qkv_w @ (g + pe) + qkv_b ; lane = v register columns
// ---------------------------------------------------------------------------
__global__ __launch_bounds__(256) void k2_qkv(
    const float* __restrict__ g_ws, const float* __restrict__ pe,
    const float* __restrict__ qw, const float* __restrict__ qb,
    float* __restrict__ qk_ws)
{
    const int t = blockIdx.x, n = blockIdx.y;
    const int v = threadIdx.x;
    if (v >= V_) return;
    float xc[C_];
    const float* gp = g_ws + (size_t)n * CTV_ + (size_t)t * V_ + v;
    const float* pp = pe + (size_t)t * V_ + v;
#pragma unroll
    for (int a = 0; a < C_; ++a) xc[a] = gp[(size_t)a * TV_] + pp[(size_t)a * TV_];
    float* op = qk_ws + (size_t)n * 96 * TV_ + (size_t)t * V_ + v;
#pragma unroll 1
    for (int j = 0; j < 96; ++j) {
        float acc = qb[j];
#pragma unroll
        for (int a = 0; a < C_; ++a) acc = fmaf(qw[j * C_ + a], xc[a], acc);
        op[(size_t)j * TV_] = acc;
    }
}

// ---------------------------------------------------------------------------
// K3a: att partials over (qc-pair) slices; block = 1 wave, lane = q,
//      K-column register-cached, Q via wave-uniform scalar loads
// grid (8, N, 12)  z: h = z>>2, t-quarter = z&3
// ---------------------------------------------------------------------------
__global__ __launch_bounds__(64) void k3_att_part(
    const float* __restrict__ qk_ws, float* __restrict__ part)
{
    const int qcg = blockIdx.x;
    const int n = blockIdx.y;
    const int h  = blockIdx.z >> 2;
    const int wv = blockIdx.z & 3;
    const int q = threadIdx.x;
    float acc[16];
#pragma unroll
    for (int i = 0; i < 16; ++i) acc[i] = 0.f;

#pragma unroll 1
    for (int qc2 = 0; qc2 < 2; ++qc2) {
        const int qc = qcg * 2 + qc2;
        const float* Qp = qk_ws + (size_t)(n * 96 + h * 16 + qc) * TV_;
        const float* Kp = qk_ws + (size_t)(n * 96 + 48 + h * 16 + qc) * TV_;
#pragma unroll 1
        for (int vc = 0; vc < 3; ++vc) {
            const int v0 = vc * 68;
            float kr[68];
            const float* kp = Kp + (size_t)q * V_ + v0;
#pragma unroll
            for (int m = 0; m < 17; ++m) {
                float4 f = *(const float4*)(kp + m * 4);
                kr[m * 4 + 0] = f.x; kr[m * 4 + 1] = f.y;
                kr[m * 4 + 2] = f.z; kr[m * 4 + 3] = f.w;
            }
#pragma unroll 1
            for (int ti = 0; ti < 16; ++ti) {
                const int tt = wv * 16 + ti;
                const float* qp = Qp + (size_t)tt * V_ + v0;
                float a = acc[ti];
#pragma unroll
                for (int vv = 0; vv < 68; ++vv) a = fmaf(qp[vv], kr[vv], a);
                acc[ti] = a;
            }
        }
    }
    float* pp = part + ((size_t)qcg * NH_ + (size_t)(n * H_ + h)) * 4096;
#pragma unroll
    for (int ti = 0; ti < 16; ++ti) pp[(wv * 16 + ti) * 64 + q] = acc[ti];
}

// K3b: att = tanh(sum(partials)/3264)*alpha + att1s
__global__ __launch_bounds__(256) void k3_att_fin(
    const float* __restrict__ part, const float* __restrict__ alphas,
    const float* __restrict__ att1s, float* __restrict__ att_ws)
{
    const int i = blockIdx.x * 256 + threadIdx.x;   // < 96*4096 exactly
    float s = 0.f;
#pragma unroll
    for (int p = 0; p < 8; ++p) s += part[(size_t)p * NH_ * 4096 + i];
    const int nh = i >> 12;
    const int h  = nh % H_;
    const int tq = i & 4095;
    att_ws[i] = tanhf(s * ATT_SC_) * alphas[h] + att1s[h * 4096 + tq];
}

// ---------------------------------------------------------------------------
// K4: y3 = leaky(bn(on_w @ einsum('nctv,nstq->nscqv', g, att) + on_b) + g)
// block = (vg, n): att column in regs (T=64), g broadcast from L1/L2,
// m staged in LDS per s, z accumulated in registers.
// ---------------------------------------------------------------------------
__global__ __launch_bounds__(256) void k4_attn(
    const float* __restrict__ g_ws, const float* __restrict__ att_ws,
    const float* __restrict__ onw, const float* __restrict__ onb,
    const float* __restrict__ bng, const float* __restrict__ bnb,
    const float* __restrict__ bnm, const float* __restrict__ bnv,
    float* __restrict__ y_out)
{
    __shared__ float4 Mt[C_ * 64];          // [c][q], f4 over v  (64 KB)
    const int vg = blockIdx.x, n = blockIdx.y;
    const int lane = threadIdx.x & 63;      // q
    const int wv = threadIdx.x >> 6;        // c-slice / o-slice
    const float* gbase = g_ws + (size_t)n * CTV_ + vg * 4;
    float4 accz[16];
#pragma unroll
    for (int i = 0; i < 16; ++i) accz[i] = make_float4(0.f, 0.f, 0.f, 0.f);

#pragma unroll 1
    for (int s = 0; s < H_; ++s) {
        // att column for this lane's q, all t, into registers
        const float* ap = att_ws + (size_t)(n * H_ + s) * 4096 + lane;
        float ar[T_];
#pragma unroll
        for (int t = 0; t < T_; ++t) ar[t] = ap[t * 64];

        // m[c, q, v4] = sum_t g[c,t,v4] * att[s,t,q]
#pragma unroll 1
        for (int ci = 0; ci < 16; ++ci) {
            const int c = wv * 16 + ci;
            const float* gp = gbase + (size_t)c * TV_;
            float4 acc = make_float4(0.f, 0.f, 0.f, 0.f);
#pragma unroll
            for (int t = 0; t < T_; ++t) {
                float4 gv = *(const float4*)(gp + (size_t)t * V_);
                acc.x = fmaf(gv.x, ar[t], acc.x);
                acc.y = fmaf(gv.y, ar[t], acc.y);
                acc.z = fmaf(gv.z, ar[t], acc.z);
                acc.w = fmaf(gv.w, ar[t], acc.w);
            }
            Mt[c * 64 + lane] = acc;
        }
        __syncthreads();

        // z[o, q, v4] += sum_c on_w[o, s*64+c] * m[c,q,v4]
#pragma unroll 1
        for (int c = 0; c < C_; ++c) {
            const float4 mv = Mt[c * 64 + lane];
#pragma unroll
            for (int oi = 0; oi < 16; ++oi) {
                const float w = onw[(wv * 16 + oi) * 192 + s * 64 + c];
                accz[oi].x = fmaf(w, mv.x, accz[oi].x);
                accz[oi].y = fmaf(w, mv.y, accz[oi].y);
                accz[oi].z = fmaf(w, mv.z, accz[oi].z);
                accz[oi].w = fmaf(w, mv.w, accz[oi].w);
            }
        }
        __syncthreads();
    }

#pragma unroll 1
    for (int oi = 0; oi < 16; ++oi) {
        const int o = wv * 16 + oi;
        const float s1 = bng[o] * rsqrtf(bnv[o] + EPS_);
        const float sh = onb[o] * s1 + bnb[o] - bnm[o] * s1;
        const float4 g4 = *(const float4*)(gbase + (size_t)o * TV_ + (size_t)lane * V_);
        float4 val;
        val.x = accz[oi].x * s1 + sh + g4.x;
        val.y = accz[oi].y * s1 + sh + g4.y;
        val.z = accz[oi].z * s1 + sh + g4.z;
        val.w = accz[oi].w * s1 + sh + g4.w;
        val.x = (val.x > 0.f) ? val.x : 0.1f * val.x;
        val.y = (val.y > 0.f) ? val.y : 0.1f * val.y;
        val.z = (val.z > 0.f) ? val.z : 0.1f * val.z;
        val.w = (val.w > 0.f) ? val.w : 0.1f * val.w;
        *(float4*)(y_out + (size_t)n * CTV_ + (size_t)o * TV_ + (size_t)lane * V_ + vg * 4) = val;
    }
}

// ---------------------------------------------------------------------------
// K5: out = leaky(bn(ff_w @ y3 + ff_b) + g), in-place on d_out
// ---------------------------------------------------------------------------
__global__ __launch_bounds__(256) void k5_ff(
    const float* __restrict__ g_ws, const float* __restrict__ fw, const float* __restrict__ fb,
    const float* __restrict__ bng, const float* __restrict__ bnb,
    const float* __restrict__ bnm, const float* __restrict__ bnv,
    float* __restrict__ io)
{
    const int t = blockIdx.x, n = blockIdx.y;
    const int v = threadIdx.x;
    if (v >= V_) return;
    float yc[C_];
    float* bp = io + (size_t)n * CTV_ + (size_t)t * V_ + v;
#pragma unroll
    for (int a = 0; a < C_; ++a) yc[a] = bp[(size_t)a * TV_];
    const float* gp = g_ws + (size_t)n * CTV_ + (size_t)t * V_ + v;
#pragma unroll 1
    for (int o = 0; o < C_; ++o) {
        float acc = fb[o];
#pragma unroll
        for (int a = 0; a < C_; ++a) acc = fmaf(fw[o * C_ + a], yc[a], acc);
        const float s1 = bng[o] * rsqrtf(bnv[o] + EPS_);
        float val = acc * s1 + (bnb[o] - bnm[o] * s1) + gp[(size_t)o * TV_];
        bp[(size_t)o * TV_] = (val > 0.f) ? val : 0.1f * val;
    }
}

// ---------------------------------------------------------------------------
extern "C" void kernel_launch(void* const* d_in, const int* in_sizes, int n_in,
                              void* d_out, int out_size, void* d_ws, size_t ws_size,
                              hipStream_t stream)
{
    (void)in_sizes; (void)n_in; (void)out_size; (void)ws_size;
    const float* x      = (const float*)d_in[0];
    const float* A      = (const float*)d_in[1];
    const float* gcn_w  = (const float*)d_in[2];
    const float* gcn_b  = (const float*)d_in[3];
    const float* gcn_g  = (const float*)d_in[4];
    const float* gcn_bb = (const float*)d_in[5];
    const float* gcn_m  = (const float*)d_in[6];
    const float* gcn_v  = (const float*)d_in[7];
    const float* pe     = (const float*)d_in[8];
    const float* qkv_w  = (const float*)d_in[9];
    const float* qkv_b  = (const float*)d_in[10];
    const float* alphas = (const float*)d_in[11];
    const float* att1s  = (const float*)d_in[12];
    const float* on_w   = (const float*)d_in[13];
    const float* on_b   = (const float*)d_in[14];
    const float* on_g   = (const float*)d_in[15];
    const float* on_bb  = (const float*)d_in[16];
    const float* on_m   = (const float*)d_in[17];
    const float* on_v   = (const float*)d_in[18];
    const float* ff_w   = (const float*)d_in[19];
    const float* ff_b   = (const float*)d_in[20];
    const float* ff_g   = (const float*)d_in[21];
    const float* ff_bb  = (const float*)d_in[22];
    const float* ff_m   = (const float*)d_in[23];
    const float* ff_v   = (const float*)d_in[24];
    float* out = (float*)d_out;

    float* g_ws    = (float*)d_ws;                         // 26,738,688 f
    float* qk_ws   = g_ws   + (size_t)N_ * CTV_;           // 40,108,032 f
    float* part_ws = qk_ws  + (size_t)N_ * 96 * TV_;       //  3,145,728 f
    float* att_ws  = part_ws + (size_t)8 * NH_ * 4096;     //    393,216 f

    k1_gcn<<<dim3(T_, N_), 256, 0, stream>>>(x, A, gcn_w, gcn_b, gcn_g, gcn_bb, gcn_m, gcn_v, g_ws);
    k2_qkv<<<dim3(T_, N_), 256, 0, stream>>>(g_ws, pe, qkv_w, qkv_b, qk_ws);
    k3_att_part<<<dim3(8, N_, 12), 64, 0, stream>>>(qk_ws, part_ws);
    k3_att_fin<<<dim3((NH_ * 4096) / 256), 256, 0, stream>>>(part_ws, alphas, att1s, att_ws);
    k4_attn<<<dim3(VG_, N_), 256, 0, stream>>>(g_ws, att_ws, on_w, on_b, on_g, on_bb, on_m, on_v, out);
    k5_ff<<<dim3(T_, N_), 256, 0, stream>>>(g_ws, ff_w, ff_b, ff_g, ff_bb, ff_m, ff_v, out);
}

// Round 2
// 2378.795 us; speedup vs baseline: 1.1999x; 1.1999x over previous
//
#include <hip/hip_runtime.h>

#define N_ 32
#define C_ 64
#define T_ 64
#define V_ 204
#define H_ 3
#define TV_ (T_ * V_)          // 13056
#define CTV_ (C_ * TV_)        // 835584
#define VG_ (V_ / 4)           // 51
#define NH_ (N_ * H_)          // 96
#define EPS_ 1e-5f
#define ATT_SC_ (1.0f / 3264.0f)
#define STV_ (H_ * TV_)        // 39168 = 192*204, per-(n,o) P slice

// ---------------------------------------------------------------------------
// K1: g = relu(bn(einsum('uv,nctv->nctu', A, W@x + b)) + x)
// block = (t, n), 256 threads
// ---------------------------------------------------------------------------
__global__ __launch_bounds__(256) void k1_gcn(
    const float* __restrict__ x, const float* __restrict__ A,
    const float* __restrict__ W, const float* __restrict__ bias,
    const float* __restrict__ bng, const float* __restrict__ bnb,
    const float* __restrict__ bnm, const float* __restrict__ bnv,
    float* __restrict__ g_out)
{
    __shared__ float Hs[C_ * 208];
    const int t = blockIdx.x, n = blockIdx.y;
    const int tid = threadIdx.x;
    const float* xp = x + (size_t)n * CTV_ + (size_t)t * V_;

    if (tid < V_) {
        float xc[C_];
#pragma unroll
        for (int a = 0; a < C_; ++a) xc[a] = xp[(size_t)a * TV_ + tid];
#pragma unroll 1
        for (int c = 0; c < C_; ++c) {
            float acc = bias[c];
#pragma unroll
            for (int a = 0; a < C_; ++a) acc = fmaf(W[c * C_ + a], xc[a], acc);
            Hs[c * 208 + tid] = acc;
        }
    }
    __syncthreads();

    const int task = tid;
    if (task < 208) {
        const int ug = task % 26, cg = task / 26;
        const int u0 = ug * 8;
        const int nu = (u0 + 8 <= V_) ? 8 : (V_ - u0);
        const int c0 = cg * 8;
        float acc[8][8];
#pragma unroll
        for (int i = 0; i < 8; ++i)
#pragma unroll
            for (int j = 0; j < 8; ++j) acc[i][j] = 0.f;

#pragma unroll 1
        for (int vg = 0; vg < VG_; ++vg) {
            float4 a4[8];
#pragma unroll
            for (int i = 0; i < 8; ++i) {
                if (i < nu) a4[i] = *(const float4*)(A + (u0 + i) * V_ + vg * 4);
                else        a4[i] = make_float4(0.f, 0.f, 0.f, 0.f);
            }
#pragma unroll
            for (int j = 0; j < 8; ++j) {
                float4 h4 = *(const float4*)(&Hs[(c0 + j) * 208 + vg * 4]);
#pragma unroll
                for (int i = 0; i < 8; ++i) {
                    acc[i][j] = fmaf(a4[i].x, h4.x, acc[i][j]);
                    acc[i][j] = fmaf(a4[i].y, h4.y, acc[i][j]);
                    acc[i][j] = fmaf(a4[i].z, h4.z, acc[i][j]);
                    acc[i][j] = fmaf(a4[i].w, h4.w, acc[i][j]);
                }
            }
        }

        float* gp = g_out + (size_t)n * CTV_ + (size_t)t * V_;
#pragma unroll 1
        for (int j = 0; j < 8; ++j) {
            const int c = c0 + j;
            const float s  = bng[c] * rsqrtf(bnv[c] + EPS_);
            const float sh = bnb[c] - bnm[c] * s;
            const float* xr = xp + (size_t)c * TV_;
            float* gr = gp + (size_t)c * TV_;
            float tmp[8];
#pragma unroll
            for (int i = 0; i < 8; ++i) {
                float xv  = (i < nu) ? xr[u0 + i] : 0.f;
                float val = acc[i][j] * s + sh + xv;
                tmp[i] = fmaxf(val, 0.f);
            }
            *(float4*)(gr + u0) = make_float4(tmp[0], tmp[1], tmp[2], tmp[3]);
            if (nu == 8)
                *(float4*)(gr + u0 + 4) = make_float4(tmp[4], tmp[5], tmp[6], tmp[7]);
        }
    }
}

// ---------------------------------------------------------------------------
// K2: qk[n, j, t, v] = qkv_w @ (g + pe) + qkv_b
// ---------------------------------------------------------------------------
__global__ __launch_bounds__(256) void k2_qkv(
    const float* __restrict__ g_ws, const float* __restrict__ pe,
    const float* __restrict__ qw, const float* __restrict__ qb,
    float* __restrict__ qk_ws)
{
    const int t = blockIdx.x, n = blockIdx.y;
    const int v = threadIdx.x;
    if (v >= V_) return;
    float xc[C_];
    const float* gp = g_ws + (size_t)n * CTV_ + (size_t)t * V_ + v;
    const float* pp = pe + (size_t)t * V_ + v;
#pragma unroll
    for (int a = 0; a < C_; ++a) xc[a] = gp[(size_t)a * TV_] + pp[(size_t)a * TV_];
    float* op = qk_ws + (size_t)n * 96 * TV_ + (size_t)t * V_ + v;
#pragma unroll 1
    for (int j = 0; j < 96; ++j) {
        float acc = qb[j];
#pragma unroll
        for (int a = 0; a < C_; ++a) acc = fmaf(qw[j * C_ + a], xc[a], acc);
        op[(size_t)j * TV_] = acc;
    }
}

// ---------------------------------------------------------------------------
// K3a: att partials; K3b: finalize
// ---------------------------------------------------------------------------
__global__ __launch_bounds__(64) void k3_att_part(
    const float* __restrict__ qk_ws, float* __restrict__ part)
{
    const int qcg = blockIdx.x;
    const int n = blockIdx.y;
    const int h  = blockIdx.z >> 2;
    const int wv = blockIdx.z & 3;
    const int q = threadIdx.x;
    float acc[16];
#pragma unroll
    for (int i = 0; i < 16; ++i) acc[i] = 0.f;

#pragma unroll 1
    for (int qc2 = 0; qc2 < 2; ++qc2) {
        const int qc = qcg * 2 + qc2;
        const float* Qp = qk_ws + (size_t)(n * 96 + h * 16 + qc) * TV_;
        const float* Kp = qk_ws + (size_t)(n * 96 + 48 + h * 16 + qc) * TV_;
#pragma unroll 1
        for (int vc = 0; vc < 3; ++vc) {
            const int v0 = vc * 68;
            float kr[68];
            const float* kp = Kp + (size_t)q * V_ + v0;
#pragma unroll
            for (int m = 0; m < 17; ++m) {
                float4 f = *(const float4*)(kp + m * 4);
                kr[m * 4 + 0] = f.x; kr[m * 4 + 1] = f.y;
                kr[m * 4 + 2] = f.z; kr[m * 4 + 3] = f.w;
            }
#pragma unroll 1
            for (int ti = 0; ti < 16; ++ti) {
                const int tt = wv * 16 + ti;
                const float* qp = Qp + (size_t)tt * V_ + v0;
                float a = acc[ti];
#pragma unroll
                for (int vv = 0; vv < 68; ++vv) a = fmaf(qp[vv], kr[vv], a);
                acc[ti] = a;
            }
        }
    }
    float* pp = part + ((size_t)qcg * NH_ + (size_t)(n * H_ + h)) * 4096;
#pragma unroll
    for (int ti = 0; ti < 16; ++ti) pp[(wv * 16 + ti) * 64 + q] = acc[ti];
}

__global__ __launch_bounds__(256) void k3_att_fin(
    const float* __restrict__ part, const float* __restrict__ alphas,
    const float* __restrict__ att1s, float* __restrict__ att_ws)
{
    const int i = blockIdx.x * 256 + threadIdx.x;
    float s = 0.f;
#pragma unroll
    for (int p = 0; p < 8; ++p) s += part[(size_t)p * NH_ * 4096 + i];
    const int nh = i >> 12;
    const int h  = nh % H_;
    const int tq = i & 4095;
    att_ws[i] = tanhf(s * ATT_SC_) * alphas[h] + att1s[h * 4096 + tq];
}

// ---------------------------------------------------------------------------
// K4a: P[n',o,s,t,v] = sum_c on_w[o, s*64+c] * g[n,c,t,v]
// grid (T_, NCHUNK), lane = v register-column GEMM, coalesced P writes.
// ---------------------------------------------------------------------------
__global__ __launch_bounds__(256) void k4a_pw(
    const float* __restrict__ g_chunk,   // g + nbase*CTV
    const float* __restrict__ onw,
    float* __restrict__ P)
{
    const int t = blockIdx.x, np = blockIdx.y;
    const int v = threadIdx.x;
    if (v >= V_) return;
    float gc[C_];
    const float* gp = g_chunk + (size_t)np * CTV_ + (size_t)t * V_ + v;
#pragma unroll
    for (int c = 0; c < C_; ++c) gc[c] = gp[(size_t)c * TV_];

    float* Pp = P + (size_t)np * 64 * STV_ + (size_t)t * V_ + v;
#pragma unroll 1
    for (int o = 0; o < 64; ++o) {
        float acc0 = 0.f, acc1 = 0.f, acc2 = 0.f;
        const float* wr = onw + o * 192;
#pragma unroll
        for (int c = 0; c < C_; ++c) {
            acc0 = fmaf(wr[c],       gc[c], acc0);
            acc1 = fmaf(wr[64 + c],  gc[c], acc1);
            acc2 = fmaf(wr[128 + c], gc[c], acc2);
        }
        float* po = Pp + (size_t)o * STV_;
        po[0]            = acc0;
        po[(size_t)TV_]  = acc1;
        po[(size_t)2 * TV_] = acc2;
    }
}

// ---------------------------------------------------------------------------
// K4b: z[n,o,q,v] = sum_st att[n,s,t,q] * P[n',o,st,v]; fused bias+BN+res+leaky
// grid (o=64, NCHUNK), 256 threads; att[n] in 48KB LDS; 16q x 4v register tile
// ---------------------------------------------------------------------------
__global__ __launch_bounds__(256) void k4b_apply(
    const float* __restrict__ P,
    const float* __restrict__ att_chunk,  // att_ws + nbase*H_*4096
    const float* __restrict__ g_chunk,    // g + nbase*CTV
    const float* __restrict__ onb,
    const float* __restrict__ bng, const float* __restrict__ bnb,
    const float* __restrict__ bnm, const float* __restrict__ bnv,
    float* __restrict__ out_chunk)        // out + nbase*CTV
{
    __shared__ float att_s[192 * 64];     // [st][q], 48 KB
    const int o = blockIdx.x, np = blockIdx.y;
    const int tid = threadIdx.x;

    // cooperative coalesced att load: 12288 floats = 3072 float4
    {
        const float4* src = (const float4*)(att_chunk + (size_t)np * (H_ * 4096));
        float4* dst = (float4*)att_s;
#pragma unroll
        for (int i = 0; i < 12; ++i) dst[tid + i * 256] = src[tid + i * 256];
    }
    __syncthreads();

    if (tid < 204) {
        const int vg = tid % 51, qg = tid / 51;
        const int v0 = vg * 4, q0 = qg * 16;

        float4 acc[16];
#pragma unroll
        for (int i = 0; i < 16; ++i) acc[i] = make_float4(0.f, 0.f, 0.f, 0.f);

        const float* Pp = P + (size_t)(np * 64 + o) * STV_ + v0;
#pragma unroll 2
        for (int st = 0; st < 192; ++st) {
            const float4 p = *(const float4*)(Pp + (size_t)st * V_);
            const float* ar = att_s + st * 64 + q0;
#pragma unroll
            for (int j = 0; j < 4; ++j) {
                const float4 a4 = *(const float4*)(ar + j * 4);
                acc[j * 4 + 0].x = fmaf(a4.x, p.x, acc[j * 4 + 0].x);
                acc[j * 4 + 0].y = fmaf(a4.x, p.y, acc[j * 4 + 0].y);
                acc[j * 4 + 0].z = fmaf(a4.x, p.z, acc[j * 4 + 0].z);
                acc[j * 4 + 0].w = fmaf(a4.x, p.w, acc[j * 4 + 0].w);
                acc[j * 4 + 1].x = fmaf(a4.y, p.x, acc[j * 4 + 1].x);
                acc[j * 4 + 1].y = fmaf(a4.y, p.y, acc[j * 4 + 1].y);
                acc[j * 4 + 1].z = fmaf(a4.y, p.z, acc[j * 4 + 1].z);
                acc[j * 4 + 1].w = fmaf(a4.y, p.w, acc[j * 4 + 1].w);
                acc[j * 4 + 2].x = fmaf(a4.z, p.x, acc[j * 4 + 2].x);
                acc[j * 4 + 2].y = fmaf(a4.z, p.y, acc[j * 4 + 2].y);
                acc[j * 4 + 2].z = fmaf(a4.z, p.z, acc[j * 4 + 2].z);
                acc[j * 4 + 2].w = fmaf(a4.z, p.w, acc[j * 4 + 2].w);
                acc[j * 4 + 3].x = fmaf(a4.w, p.x, acc[j * 4 + 3].x);
                acc[j * 4 + 3].y = fmaf(a4.w, p.y, acc[j * 4 + 3].y);
                acc[j * 4 + 3].z = fmaf(a4.w, p.z, acc[j * 4 + 3].z);
                acc[j * 4 + 3].w = fmaf(a4.w, p.w, acc[j * 4 + 3].w);
            }
        }

        const float s1 = bng[o] * rsqrtf(bnv[o] + EPS_);
        const float sh = onb[o] * s1 + bnb[o] - bnm[o] * s1;
        const float* gp = g_chunk + (size_t)np * CTV_ + (size_t)o * TV_ + v0;
        float* zp = out_chunk + (size_t)np * CTV_ + (size_t)o * TV_ + v0;
#pragma unroll 1
        for (int i = 0; i < 16; ++i) {
            const int q = q0 + i;
            const float4 g4 = *(const float4*)(gp + (size_t)q * V_);
            float4 val;
            val.x = acc[i].x * s1 + sh + g4.x;
            val.y = acc[i].y * s1 + sh + g4.y;
            val.z = acc[i].z * s1 + sh + g4.z;
            val.w = acc[i].w * s1 + sh + g4.w;
            val.x = (val.x > 0.f) ? val.x : 0.1f * val.x;
            val.y = (val.y > 0.f) ? val.y : 0.1f * val.y;
            val.z = (val.z > 0.f) ? val.z : 0.1f * val.z;
            val.w = (val.w > 0.f) ? val.w : 0.1f * val.w;
            *(float4*)(zp + (size_t)q * V_) = val;
        }
    }
}

// ---------------------------------------------------------------------------
// K5: out = leaky(bn(ff_w @ y3 + ff_b) + g), in-place on d_out
// ---------------------------------------------------------------------------
__global__ __launch_bounds__(256) void k5_ff(
    const float* __restrict__ g_ws, const float* __restrict__ fw, const float* __restrict__ fb,
    const float* __restrict__ bng, const float* __restrict__ bnb,
    const float* __restrict__ bnm, const float* __restrict__ bnv,
    float* __restrict__ io)
{
    const int t = blockIdx.x, n = blockIdx.y;
    const int v = threadIdx.x;
    if (v >= V_) return;
    float yc[C_];
    float* bp = io + (size_t)n * CTV_ + (size_t)t * V_ + v;
#pragma unroll
    for (int a = 0; a < C_; ++a) yc[a] = bp[(size_t)a * TV_];
    const float* gp = g_ws + (size_t)n * CTV_ + (size_t)t * V_ + v;
#pragma unroll 1
    for (int o = 0; o < C_; ++o) {
        float acc = fb[o];
#pragma unroll
        for (int a = 0; a < C_; ++a) acc = fmaf(fw[o * C_ + a], yc[a], acc);
        const float s1 = bng[o] * rsqrtf(bnv[o] + EPS_);
        float val = acc * s1 + (bnb[o] - bnm[o] * s1) + gp[(size_t)o * TV_];
        bp[(size_t)o * TV_] = (val > 0.f) ? val : 0.1f * val;
    }
}

// ---------------------------------------------------------------------------
extern "C" void kernel_launch(void* const* d_in, const int* in_sizes, int n_in,
                              void* d_out, int out_size, void* d_ws, size_t ws_size,
                              hipStream_t stream)
{
    (void)in_sizes; (void)n_in; (void)out_size; (void)ws_size;
    const float* x      = (const float*)d_in[0];
    const float* A      = (const float*)d_in[1];
    const float* gcn_w  = (const float*)d_in[2];
    const float* gcn_b  = (const float*)d_in[3];
    const float* gcn_g  = (const float*)d_in[4];
    const float* gcn_bb = (const float*)d_in[5];
    const float* gcn_m  = (const float*)d_in[6];
    const float* gcn_v  = (const float*)d_in[7];
    const float* pe     = (const float*)d_in[8];
    const float* qkv_w  = (const float*)d_in[9];
    const float* qkv_b  = (const float*)d_in[10];
    const float* alphas = (const float*)d_in[11];
    const float* att1s  = (const float*)d_in[12];
    const float* on_w   = (const float*)d_in[13];
    const float* on_b   = (const float*)d_in[14];
    const float* on_g   = (const float*)d_in[15];
    const float* on_bb  = (const float*)d_in[16];
    const float* on_m   = (const float*)d_in[17];
    const float* on_v   = (const float*)d_in[18];
    const float* ff_w   = (const float*)d_in[19];
    const float* ff_b   = (const float*)d_in[20];
    const float* ff_g   = (const float*)d_in[21];
    const float* ff_bb  = (const float*)d_in[22];
    const float* ff_m   = (const float*)d_in[23];
    const float* ff_v   = (const float*)d_in[24];
    float* out = (float*)d_out;

    float* g_ws    = (float*)d_ws;                         // 26,738,688 f
    float* qk_ws   = g_ws   + (size_t)N_ * CTV_;           // 40,108,032 f (aliased by P)
    float* part_ws = qk_ws  + (size_t)N_ * 96 * TV_;       //  3,145,728 f
    float* att_ws  = part_ws + (size_t)8 * NH_ * 4096;     //    393,216 f
    float* P_ws    = qk_ws;  // alias: qk dead after k3; exactly 16*64*STV_ floats

    k1_gcn<<<dim3(T_, N_), 256, 0, stream>>>(x, A, gcn_w, gcn_b, gcn_g, gcn_bb, gcn_m, gcn_v, g_ws);
    k2_qkv<<<dim3(T_, N_), 256, 0, stream>>>(g_ws, pe, qkv_w, qkv_b, qk_ws);
    k3_att_part<<<dim3(8, N_, 12), 64, 0, stream>>>(qk_ws, part_ws);
    k3_att_fin<<<dim3((NH_ * 4096) / 256), 256, 0, stream>>>(part_ws, alphas, att1s, att_ws);

    for (int chunk = 0; chunk < 2; ++chunk) {
        const int nb = chunk * 16;
        k4a_pw<<<dim3(T_, 16), 256, 0, stream>>>(g_ws + (size_t)nb * CTV_, on_w, P_ws);
        k4b_apply<<<dim3(64, 16), 256, 0, stream>>>(
            P_ws, att_ws + (size_t)nb * H_ * 4096, g_ws + (size_t)nb * CTV_,
            on_b, on_g, on_bb, on_m, on_v, out + (size_t)nb * CTV_);
    }
    k5_ff<<<dim3(T_, N_), 256, 0, stream>>>(g_ws, ff_w, ff_b, ff_g, ff_bb, ff_m, ff_v, out);
}

// Round 3
// 2136.817 us; speedup vs baseline: 1.3358x; 1.1132x over previous
//
#include <hip/hip_runtime.h>

#define N_ 32
#define C_ 64
#define T_ 64
#define V_ 204
#define H_ 3
#define TV_ (T_ * V_)          // 13056
#define CTV_ (C_ * TV_)        // 835584
#define VG_ (V_ / 4)           // 51
#define NH_ (N_ * H_)          // 96
#define EPS_ 1e-5f
#define ATT_SC_ (1.0f / 3264.0f)
#define STV_ (H_ * TV_)        // 39168
#define KP_ 224                // padded K (v) for MFMA
#define UP_ 208                // padded u rows of A

typedef __bf16 bf16x8 __attribute__((ext_vector_type(8)));
typedef float  f32x4  __attribute__((ext_vector_type(4)));

// ---------------------------------------------------------------------------
// K0: Apad[u][v] = bf16(A[u][v]) zero-padded to 208x224
// ---------------------------------------------------------------------------
__global__ __launch_bounds__(224) void k0_cvtA(
    const float* __restrict__ A, __bf16* __restrict__ Apad)
{
    const int u = blockIdx.x;       // 0..207
    const int v = threadIdx.x;      // 0..223
    float val = (u < V_ && v < V_) ? A[u * V_ + v] : 0.f;
    Apad[u * KP_ + v] = (__bf16)val;
}

// ---------------------------------------------------------------------------
// K1a: h[r][v] = bf16(bias[c] + sum_a W[c,a] x[n,a,t,v]), r=(n,c,t), row KP_
// ---------------------------------------------------------------------------
__global__ __launch_bounds__(256) void k1a_h(
    const float* __restrict__ x, const float* __restrict__ W,
    const float* __restrict__ bias, __bf16* __restrict__ h)
{
    const int t = blockIdx.x, n = blockIdx.y;
    const int v = threadIdx.x;
    if (v >= KP_) return;
    __bf16* hp = h + ((size_t)n * 4096 + t) * KP_ + v;   // + c*64*KP_ per row
    if (v >= V_) {
#pragma unroll 1
        for (int c = 0; c < C_; ++c) hp[(size_t)c * 64 * KP_] = (__bf16)0.f;
        return;
    }
    float xc[C_];
    const float* xp = x + (size_t)n * CTV_ + (size_t)t * V_ + v;
#pragma unroll
    for (int a = 0; a < C_; ++a) xc[a] = xp[(size_t)a * TV_];
#pragma unroll 1
    for (int c = 0; c < C_; ++c) {
        float acc = bias[c];
#pragma unroll
        for (int a = 0; a < C_; ++a) acc = fmaf(W[c * C_ + a], xc[a], acc);
        hp[(size_t)c * 64 * KP_] = (__bf16)acc;
    }
}

// ---------------------------------------------------------------------------
// K1b: G[r,u] = sum_v h[r,v] * Apad[u,v]  (MFMA 16x16x32 bf16)
//      g = relu(s*G + sh + x) fused epilogue. 2048 blocks x 256 thr, no LDS.
// ---------------------------------------------------------------------------
__global__ __launch_bounds__(256) void k1b_mfma(
    const __bf16* __restrict__ h, const __bf16* __restrict__ Apad,
    const float* __restrict__ x,
    const float* __restrict__ bng, const float* __restrict__ bnb,
    const float* __restrict__ bnm, const float* __restrict__ bnv,
    float* __restrict__ g_out)
{
    const int wave = threadIdx.x >> 6;
    const int lane = threadIdx.x & 63;
    const int l16  = lane & 15;
    const int quad = lane >> 4;

    const __bf16* hA = h + (size_t)(blockIdx.x * 64 + wave * 16 + l16) * KP_ + quad * 8;
    const __bf16* Bp = Apad + (size_t)l16 * KP_ + quad * 8;

    f32x4 acc[13];
#pragma unroll
    for (int j = 0; j < 13; ++j) acc[j] = (f32x4){0.f, 0.f, 0.f, 0.f};

#pragma unroll 1
    for (int kc = 0; kc < 7; ++kc) {
        const bf16x8 af = *(const bf16x8*)(hA + kc * 32);
        bf16x8 bf[13];
#pragma unroll
        for (int j = 0; j < 13; ++j)
            bf[j] = *(const bf16x8*)(Bp + (size_t)j * 16 * KP_ + kc * 32);
#pragma unroll
        for (int j = 0; j < 13; ++j)
            acc[j] = __builtin_amdgcn_mfma_f32_16x16x32_bf16(af, bf[j], acc[j], 0, 0, 0);
    }

    // epilogue: block covers exactly one (n,c), t = 0..63
    const int c = blockIdx.x & 63;
    const float s1 = bng[c] * rsqrtf(bnv[c] + EPS_);
    const float sh = bnb[c] - bnm[c] * s1;
    const int rbase = blockIdx.x * 64 + wave * 16 + quad * 4;

#pragma unroll 1
    for (int j = 0; j < 13; ++j) {
        const int u = j * 16 + l16;
        if (u < V_) {
#pragma unroll
            for (int i = 0; i < 4; ++i) {
                const size_t r = (size_t)(rbase + i);
                const float val = acc[j][i] * s1 + sh + x[r * V_ + u];
                g_out[r * V_ + u] = fmaxf(val, 0.f);
            }
        }
    }
}

// ---------------------------------------------------------------------------
// K2: qk[n, j, t, v] = qkv_w @ (g + pe) + qkv_b
// ---------------------------------------------------------------------------
__global__ __launch_bounds__(256) void k2_qkv(
    const float* __restrict__ g_ws, const float* __restrict__ pe,
    const float* __restrict__ qw, const float* __restrict__ qb,
    float* __restrict__ qk_ws)
{
    const int t = blockIdx.x, n = blockIdx.y;
    const int v = threadIdx.x;
    if (v >= V_) return;
    float xc[C_];
    const float* gp = g_ws + (size_t)n * CTV_ + (size_t)t * V_ + v;
    const float* pp = pe + (size_t)t * V_ + v;
#pragma unroll
    for (int a = 0; a < C_; ++a) xc[a] = gp[(size_t)a * TV_] + pp[(size_t)a * TV_];
    float* op = qk_ws + (size_t)n * 96 * TV_ + (size_t)t * V_ + v;
#pragma unroll 1
    for (int j = 0; j < 96; ++j) {
        float acc = qb[j];
#pragma unroll
        for (int a = 0; a < C_; ++a) acc = fmaf(qw[j * C_ + a], xc[a], acc);
        op[(size_t)j * TV_] = acc;
    }
}

// ---------------------------------------------------------------------------
// K3a: att partials; K3b: finalize
// ---------------------------------------------------------------------------
__global__ __launch_bounds__(64) void k3_att_part(
    const float* __restrict__ qk_ws, float* __restrict__ part)
{
    const int qcg = blockIdx.x;
    const int n = blockIdx.y;
    const int h  = blockIdx.z >> 2;
    const int wv = blockIdx.z & 3;
    const int q = threadIdx.x;
    float acc[16];
#pragma unroll
    for (int i = 0; i < 16; ++i) acc[i] = 0.f;

#pragma unroll 1
    for (int qc2 = 0; qc2 < 2; ++qc2) {
        const int qc = qcg * 2 + qc2;
        const float* Qp = qk_ws + (size_t)(n * 96 + h * 16 + qc) * TV_;
        const float* Kp = qk_ws + (size_t)(n * 96 + 48 + h * 16 + qc) * TV_;
#pragma unroll 1
        for (int vc = 0; vc < 3; ++vc) {
            const int v0 = vc * 68;
            float kr[68];
            const float* kp = Kp + (size_t)q * V_ + v0;
#pragma unroll
            for (int m = 0; m < 17; ++m) {
                float4 f = *(const float4*)(kp + m * 4);
                kr[m * 4 + 0] = f.x; kr[m * 4 + 1] = f.y;
                kr[m * 4 + 2] = f.z; kr[m * 4 + 3] = f.w;
            }
#pragma unroll 1
            for (int ti = 0; ti < 16; ++ti) {
                const int tt = wv * 16 + ti;
                const float* qp = Qp + (size_t)tt * V_ + v0;
                float a = acc[ti];
#pragma unroll
                for (int vv = 0; vv < 68; ++vv) a = fmaf(qp[vv], kr[vv], a);
                acc[ti] = a;
            }
        }
    }
    float* pp = part + ((size_t)qcg * NH_ + (size_t)(n * H_ + h)) * 4096;
#pragma unroll
    for (int ti = 0; ti < 16; ++ti) pp[(wv * 16 + ti) * 64 + q] = acc[ti];
}

__global__ __launch_bounds__(256) void k3_att_fin(
    const float* __restrict__ part, const float* __restrict__ alphas,
    const float* __restrict__ att1s, float* __restrict__ att_ws)
{
    const int i = blockIdx.x * 256 + threadIdx.x;
    float s = 0.f;
#pragma unroll
    for (int p = 0; p < 8; ++p) s += part[(size_t)p * NH_ * 4096 + i];
    const int nh = i >> 12;
    const int h  = nh % H_;
    const int tq = i & 4095;
    att_ws[i] = tanhf(s * ATT_SC_) * alphas[h] + att1s[h * 4096 + tq];
}

// ---------------------------------------------------------------------------
// K4a: P[n',o,s,t,v] = sum_c on_w[o, s*64+c] * g[n,c,t,v]
// ---------------------------------------------------------------------------
__global__ __launch_bounds__(256) void k4a_pw(
    const float* __restrict__ g_chunk,
    const float* __restrict__ onw,
    float* __restrict__ P)
{
    const int t = blockIdx.x, np = blockIdx.y;
    const int v = threadIdx.x;
    if (v >= V_) return;
    float gc[C_];
    const float* gp = g_chunk + (size_t)np * CTV_ + (size_t)t * V_ + v;
#pragma unroll
    for (int c = 0; c < C_; ++c) gc[c] = gp[(size_t)c * TV_];

    float* Pp = P + (size_t)np * 64 * STV_ + (size_t)t * V_ + v;
#pragma unroll 1
    for (int o = 0; o < 64; ++o) {
        float acc0 = 0.f, acc1 = 0.f, acc2 = 0.f;
        const float* wr = onw + o * 192;
#pragma unroll
        for (int c = 0; c < C_; ++c) {
            acc0 = fmaf(wr[c],       gc[c], acc0);
            acc1 = fmaf(wr[64 + c],  gc[c], acc1);
            acc2 = fmaf(wr[128 + c], gc[c], acc2);
        }
        float* po = Pp + (size_t)o * STV_;
        po[0]               = acc0;
        po[(size_t)TV_]     = acc1;
        po[(size_t)2 * TV_] = acc2;
    }
}

// ---------------------------------------------------------------------------
// K4b: z[n,o,q,v] = sum_st att[n,s,t,q] * P[n',o,st,v]; fused epilogue
// ---------------------------------------------------------------------------
__global__ __launch_bounds__(256) void k4b_apply(
    const float* __restrict__ P,
    const float* __restrict__ att_chunk,
    const float* __restrict__ g_chunk,
    const float* __restrict__ onb,
    const float* __restrict__ bng, const float* __restrict__ bnb,
    const float* __restrict__ bnm, const float* __restrict__ bnv,
    float* __restrict__ out_chunk)
{
    __shared__ float att_s[192 * 64];
    const int o = blockIdx.x, np = blockIdx.y;
    const int tid = threadIdx.x;

    {
        const float4* src = (const float4*)(att_chunk + (size_t)np * (H_ * 4096));
        float4* dst = (float4*)att_s;
#pragma unroll
        for (int i = 0; i < 12; ++i) dst[tid + i * 256] = src[tid + i * 256];
    }
    __syncthreads();

    if (tid < 204) {
        const int vg = tid % 51, qg = tid / 51;
        const int v0 = vg * 4, q0 = qg * 16;

        float4 acc[16];
#pragma unroll
        for (int i = 0; i < 16; ++i) acc[i] = make_float4(0.f, 0.f, 0.f, 0.f);

        const float* Pp = P + (size_t)(np * 64 + o) * STV_ + v0;
#pragma unroll 2
        for (int st = 0; st < 192; ++st) {
            const float4 p = *(const float4*)(Pp + (size_t)st * V_);
            const float* ar = att_s + st * 64 + q0;
#pragma unroll
            for (int j = 0; j < 4; ++j) {
                const float4 a4 = *(const float4*)(ar + j * 4);
                acc[j * 4 + 0].x = fmaf(a4.x, p.x, acc[j * 4 + 0].x);
                acc[j * 4 + 0].y = fmaf(a4.x, p.y, acc[j * 4 + 0].y);
                acc[j * 4 + 0].z = fmaf(a4.x, p.z, acc[j * 4 + 0].z);
                acc[j * 4 + 0].w = fmaf(a4.x, p.w, acc[j * 4 + 0].w);
                acc[j * 4 + 1].x = fmaf(a4.y, p.x, acc[j * 4 + 1].x);
                acc[j * 4 + 1].y = fmaf(a4.y, p.y, acc[j * 4 + 1].y);
                acc[j * 4 + 1].z = fmaf(a4.y, p.z, acc[j * 4 + 1].z);
                acc[j * 4 + 1].w = fmaf(a4.y, p.w, acc[j * 4 + 1].w);
                acc[j * 4 + 2].x = fmaf(a4.z, p.x, acc[j * 4 + 2].x);
                acc[j * 4 + 2].y = fmaf(a4.z, p.y, acc[j * 4 + 2].y);
                acc[j * 4 + 2].z = fmaf(a4.z, p.z, acc[j * 4 + 2].z);
                acc[j * 4 + 2].w = fmaf(a4.z, p.w, acc[j * 4 + 2].w);
                acc[j * 4 + 3].x = fmaf(a4.w, p.x, acc[j * 4 + 3].x);
                acc[j * 4 + 3].y = fmaf(a4.w, p.y, acc[j * 4 + 3].y);
                acc[j * 4 + 3].z = fmaf(a4.w, p.z, acc[j * 4 + 3].z);
                acc[j * 4 + 3].w = fmaf(a4.w, p.w, acc[j * 4 + 3].w);
            }
        }

        const float s1 = bng[o] * rsqrtf(bnv[o] + EPS_);
        const float sh = onb[o] * s1 + bnb[o] - bnm[o] * s1;
        const float* gp = g_chunk + (size_t)np * CTV_ + (size_t)o * TV_ + v0;
        float* zp = out_chunk + (size_t)np * CTV_ + (size_t)o * TV_ + v0;
#pragma unroll 1
        for (int i = 0; i < 16; ++i) {
            const int q = q0 + i;
            const float4 g4 = *(const float4*)(gp + (size_t)q * V_);
            float4 val;
            val.x = acc[i].x * s1 + sh + g4.x;
            val.y = acc[i].y * s1 + sh + g4.y;
            val.z = acc[i].z * s1 + sh + g4.z;
            val.w = acc[i].w * s1 + sh + g4.w;
            val.x = (val.x > 0.f) ? val.x : 0.1f * val.x;
            val.y = (val.y > 0.f) ? val.y : 0.1f * val.y;
            val.z = (val.z > 0.f) ? val.z : 0.1f * val.z;
            val.w = (val.w > 0.f) ? val.w : 0.1f * val.w;
            *(float4*)(zp + (size_t)q * V_) = val;
        }
    }
}

// ---------------------------------------------------------------------------
// K5: out = leaky(bn(ff_w @ y3 + ff_b) + g), in-place on d_out
// ---------------------------------------------------------------------------
__global__ __launch_bounds__(256) void k5_ff(
    const float* __restrict__ g_ws, const float* __restrict__ fw, const float* __restrict__ fb,
    const float* __restrict__ bng, const float* __restrict__ bnb,
    const float* __restrict__ bnm, const float* __restrict__ bnv,
    float* __restrict__ io)
{
    const int t = blockIdx.x, n = blockIdx.y;
    const int v = threadIdx.x;
    if (v >= V_) return;
    float yc[C_];
    float* bp = io + (size_t)n * CTV_ + (size_t)t * V_ + v;
#pragma unroll
    for (int a = 0; a < C_; ++a) yc[a] = bp[(size_t)a * TV_];
    const float* gp = g_ws + (size_t)n * CTV_ + (size_t)t * V_ + v;
#pragma unroll 1
    for (int o = 0; o < C_; ++o) {
        float acc = fb[o];
#pragma unroll
        for (int a = 0; a < C_; ++a) acc = fmaf(fw[o * C_ + a], yc[a], acc);
        const float s1 = bng[o] * rsqrtf(bnv[o] + EPS_);
        float val = acc * s1 + (bnb[o] - bnm[o] * s1) + gp[(size_t)o * TV_];
        bp[(size_t)o * TV_] = (val > 0.f) ? val : 0.1f * val;
    }
}

// ---------------------------------------------------------------------------
extern "C" void kernel_launch(void* const* d_in, const int* in_sizes, int n_in,
                              void* d_out, int out_size, void* d_ws, size_t ws_size,
                              hipStream_t stream)
{
    (void)in_sizes; (void)n_in; (void)out_size; (void)ws_size;
    const float* x      = (const float*)d_in[0];
    const float* A      = (const float*)d_in[1];
    const float* gcn_w  = (const float*)d_in[2];
    const float* gcn_b  = (const float*)d_in[3];
    const float* gcn_g  = (const float*)d_in[4];
    const float* gcn_bb = (const float*)d_in[5];
    const float* gcn_m  = (const float*)d_in[6];
    const float* gcn_v  = (const float*)d_in[7];
    const float* pe     = (const float*)d_in[8];
    const float* qkv_w  = (const float*)d_in[9];
    const float* qkv_b  = (const float*)d_in[10];
    const float* alphas = (const float*)d_in[11];
    const float* att1s  = (const float*)d_in[12];
    const float* on_w   = (const float*)d_in[13];
    const float* on_b   = (const float*)d_in[14];
    const float* on_g   = (const float*)d_in[15];
    const float* on_bb  = (const float*)d_in[16];
    const float* on_m   = (const float*)d_in[17];
    const float* on_v   = (const float*)d_in[18];
    const float* ff_w   = (const float*)d_in[19];
    const float* ff_b   = (const float*)d_in[20];
    const float* ff_g   = (const float*)d_in[21];
    const float* ff_bb  = (const float*)d_in[22];
    const float* ff_m   = (const float*)d_in[23];
    const float* ff_v   = (const float*)d_in[24];
    float* out = (float*)d_out;

    float* g_ws    = (float*)d_ws;                         // 26,738,688 f
    float* qk_ws   = g_ws   + (size_t)N_ * CTV_;           // 40,108,032 f
    float* part_ws = qk_ws  + (size_t)N_ * 96 * TV_;       //  3,145,728 f
    float* att_ws  = part_ws + (size_t)8 * NH_ * 4096;     //    393,216 f
    float* P_ws    = qk_ws;                                // alias (qk dead after k3)
    __bf16* h_ws   = (__bf16*)qk_ws;                       // alias (dead before k2 writes)
    __bf16* Apad   = (__bf16*)part_ws;                     // alias (dead before k3a writes)

    k0_cvtA<<<dim3(UP_), 224, 0, stream>>>(A, Apad);
    k1a_h  <<<dim3(T_, N_), 256, 0, stream>>>(x, gcn_w, gcn_b, h_ws);
    k1b_mfma<<<dim3(2048), 256, 0, stream>>>(h_ws, Apad, x,
                                             gcn_g, gcn_bb, gcn_m, gcn_v, g_ws);
    k2_qkv<<<dim3(T_, N_), 256, 0, stream>>>(g_ws, pe, qkv_w, qkv_b, qk_ws);
    k3_att_part<<<dim3(8, N_, 12), 64, 0, stream>>>(qk_ws, part_ws);
    k3_att_fin<<<dim3((NH_ * 4096) / 256), 256, 0, stream>>>(part_ws, alphas, att1s, att_ws);

    for (int chunk = 0; chunk < 2; ++chunk) {
        const int nb = chunk * 16;
        k4a_pw<<<dim3(T_, 16), 256, 0, stream>>>(g_ws + (size_t)nb * CTV_, on_w, P_ws);
        k4b_apply<<<dim3(64, 16), 256, 0, stream>>>(
            P_ws, att_ws + (size_t)nb * H_ * 4096, g_ws + (size_t)nb * CTV_,
            on_b, on_g, on_bb, on_m, on_v, out + (size_t)nb * CTV_);
    }
    k5_ff<<<dim3(T_, N_), 256, 0, stream>>>(g_ws, ff_w, ff_b, ff_g, ff_bb, ff_m, ff_v, out);
}